// Round 1
// baseline (424.630 us; speedup 1.0000x reference)
//
#include <hip/hip_runtime.h>
#include <hip/hip_bf16.h>

// SlotAttention: B=32, N=16384, D=64, S=7, H=128, 3 iterations.
//   proj_kernel : LN(inputs) -> k[b][n][d] + vT[b][d][n] (bf16, MFMA, coalesced LDS epilogue)
//   init_kernel : slots0, h0, q0
//   3x { attn_kernel : MFMA logits -> no-max softmax (octet sum shuffles) -> MFMA attn@v,
//                      per-block partial outputs (no atomics)
//        slot_update : partial-sum -> GRU (w_hhT in LDS) -> MLP -> slots -> next q }

#define B_ 32
#define N_ 16384
#define D_ 64
#define S_ 7

typedef __bf16 bf16x8 __attribute__((ext_vector_type(8)));
typedef float floatx4 __attribute__((ext_vector_type(4)));

__device__ __forceinline__ unsigned int f2bfu(float f) {
  __hip_bfloat16 h = __float2bfloat16(f);
  return (unsigned int)__builtin_bit_cast(unsigned short, h);
}
__device__ __forceinline__ unsigned int pack2bf(float lo, float hi) {
  return f2bfu(lo) | (f2bfu(hi) << 16);
}

// ---------------- proj: LN + K/V projection ----------------
// k[b][n][d]: attn phase-1 A-frags read 16B/lane directly from global.
// vT[b][d][n]: attn phase-2 B-frags read 16B/lane directly from global.
__global__ __launch_bounds__(256) void proj_kernel(
    const float* __restrict__ x,
    const float* __restrict__ lng, const float* __restrict__ lnb,
    const float* __restrict__ Wk, const float* __restrict__ Wv,
    unsigned short* __restrict__ kb, unsigned short* __restrict__ vt)
{
  __shared__ __align__(16) unsigned char smem[32768];
  unsigned short* s_xn = (unsigned short*)smem;            // [128][64] xor-swizzled
  unsigned short* s_w  = (unsigned short*)(smem + 16384);  // [128][64]
  unsigned short* s_ko = (unsigned short*)smem;            // reuse: k_out [128][72]
  unsigned short* s_vo = (unsigned short*)smem;            // reuse: v_out [64][136]

  const int t = threadIdx.x, lane = t & 63, w = t >> 6;
  const int R0 = blockIdx.x * 128;
  const int bb = R0 >> 14;          // batch (16384 rows per b)
  const int nbase = R0 & (N_ - 1);

  // stage weights: consecutive 16B per thread (conflict-free)
#pragma unroll
  for (int p = 0; p < 4; ++p) {
    int idx = (p * 256 + t) * 8;
    const float* src = (idx < 4096) ? (Wk + idx) : (Wv + idx - 4096);
    float4 a = ((const float4*)src)[0], b = ((const float4*)src)[1];
    uint4 pk;
    pk.x = pack2bf(a.x, a.y); pk.y = pack2bf(a.z, a.w);
    pk.z = pack2bf(b.x, b.y); pk.w = pack2bf(b.z, b.w);
    *(uint4*)&s_w[idx] = pk;
  }

  // LayerNorm: 4 lanes per row, 16 f32 each
  const int ql = t & 3;
  float4 g4[4], b4[4];
#pragma unroll
  for (int j = 0; j < 4; ++j) {
    g4[j] = *(const float4*)&lng[ql * 16 + j * 4];
    b4[j] = *(const float4*)&lnb[ql * 16 + j * 4];
  }
#pragma unroll
  for (int half = 0; half < 2; ++half) {
    int r = half * 64 + (t >> 2);
    const float4* xp = (const float4*)&x[(size_t)(R0 + r) * 64 + ql * 16];
    float4 xv[4];
#pragma unroll
    for (int j = 0; j < 4; ++j) xv[j] = xp[j];
    float s1 = 0.f, s2 = 0.f;
#pragma unroll
    for (int j = 0; j < 4; ++j) {
      s1 += xv[j].x + xv[j].y + xv[j].z + xv[j].w;
      s2 += xv[j].x * xv[j].x + xv[j].y * xv[j].y + xv[j].z * xv[j].z + xv[j].w * xv[j].w;
    }
    s1 += __shfl_xor(s1, 1); s2 += __shfl_xor(s2, 1);
    s1 += __shfl_xor(s1, 2); s2 += __shfl_xor(s2, 2);
    float mean = s1 * 0.015625f;
    float var = s2 * 0.015625f - mean * mean;
    float rs = rsqrtf(var + 1e-5f);
    float y[16];
#pragma unroll
    for (int j = 0; j < 4; ++j) {
      y[j * 4 + 0] = (xv[j].x - mean) * rs * g4[j].x + b4[j].x;
      y[j * 4 + 1] = (xv[j].y - mean) * rs * g4[j].y + b4[j].y;
      y[j * 4 + 2] = (xv[j].z - mean) * rs * g4[j].z + b4[j].z;
      y[j * 4 + 3] = (xv[j].w - mean) * rs * g4[j].w + b4[j].w;
    }
#pragma unroll
    for (int h = 0; h < 2; ++h) {
      uint4 p;
      p.x = pack2bf(y[h * 8 + 0], y[h * 8 + 1]);
      p.y = pack2bf(y[h * 8 + 2], y[h * 8 + 3]);
      p.z = pack2bf(y[h * 8 + 4], y[h * 8 + 5]);
      p.w = pack2bf(y[h * 8 + 6], y[h * 8 + 7]);
      int c = ql * 2 + h;
      int sc = c ^ (r & 7);
      *(uint4*)&s_xn[r * 64 + sc * 8] = p;
    }
  }
  __syncthreads();

  const int m16 = lane & 15, quad = lane >> 4;
  // preload ALL fragments (s_xn/s_w dead afterwards -> reuse for outputs)
  bf16x8 bf[2][2];   // xn: lane m16 = xrow-within-tile, k = quad*8+j (+32)
#pragma unroll
  for (int rt = 0; rt < 2; ++rt) {
    int xr = (w * 2 + rt) * 16 + m16;
#pragma unroll
    for (int kk = 0; kk < 2; ++kk)
      bf[rt][kk] = *(const bf16x8*)&s_xn[xr * 64 + (((kk * 4 + quad) ^ (xr & 7)) * 8)];
  }
  bf16x8 wkf[4][2], wvf[4][2];
#pragma unroll
  for (int ft = 0; ft < 4; ++ft)
#pragma unroll
    for (int kk = 0; kk < 2; ++kk) {
      wkf[ft][kk] = *(const bf16x8*)&s_w[(ft * 16 + m16) * 64 + kk * 32 + quad * 8];
      wvf[ft][kk] = *(const bf16x8*)&s_w[(64 + ft * 16 + m16) * 64 + kk * 32 + quad * 8];
    }
  __syncthreads();

  // k-part: A=Wk (m=d), B=xn (n'=n). D: d = ft*16+quad*4+rg, n = tile_rt*16+m16
#pragma unroll
  for (int ft = 0; ft < 4; ++ft)
#pragma unroll
    for (int rt = 0; rt < 2; ++rt) {
      floatx4 acc = (floatx4){0.f, 0.f, 0.f, 0.f};
      acc = __builtin_amdgcn_mfma_f32_16x16x32_bf16(wkf[ft][0], bf[rt][0], acc, 0, 0, 0);
      acc = __builtin_amdgcn_mfma_f32_16x16x32_bf16(wkf[ft][1], bf[rt][1], acc, 0, 0, 0);
      int n_l = (w * 2 + rt) * 16 + m16;
      uint2 p;
      p.x = pack2bf(acc[0], acc[1]);
      p.y = pack2bf(acc[2], acc[3]);
      *(uint2*)&s_ko[n_l * 72 + ft * 16 + quad * 4] = p;
    }
  __syncthreads();
  // coalesced k store: linear [n][d]
#pragma unroll
  for (int p = 0; p < 4; ++p) {
    int ii = (p * 256 + t) * 8;
    int n_l = ii >> 6, dl = ii & 63;
    uint4 v4 = *(const uint4*)&s_ko[n_l * 72 + dl];
    *(uint4*)&kb[(size_t)(R0 + n_l) * 64 + dl] = v4;
  }
  __syncthreads();

  // v-part: A=xn (m=n), B=Wv (n'=d). D: n = tile_rt*16+quad*4+rg, d = ft*16+m16
#pragma unroll
  for (int ft = 0; ft < 4; ++ft)
#pragma unroll
    for (int rt = 0; rt < 2; ++rt) {
      floatx4 acc = (floatx4){0.f, 0.f, 0.f, 0.f};
      acc = __builtin_amdgcn_mfma_f32_16x16x32_bf16(bf[rt][0], wvf[ft][0], acc, 0, 0, 0);
      acc = __builtin_amdgcn_mfma_f32_16x16x32_bf16(bf[rt][1], wvf[ft][1], acc, 0, 0, 0);
      int n_l = (w * 2 + rt) * 16 + quad * 4;
      int d0 = ft * 16 + m16;
      uint2 p;
      p.x = pack2bf(acc[0], acc[1]);
      p.y = pack2bf(acc[2], acc[3]);
      *(uint2*)&s_vo[d0 * 136 + n_l] = p;
    }
  __syncthreads();
  // coalesced vT store: rows d, 128 n per row
#pragma unroll
  for (int p = 0; p < 4; ++p) {
    int ii = (p * 256 + t) * 8;
    int d0 = ii >> 7, nl = ii & 127;
    uint4 v4 = *(const uint4*)&s_vo[d0 * 136 + nl];
    *(uint4*)&vt[((size_t)bb * 64 + d0) * N_ + nbase + nl] = v4;
  }
}

// ---------------- shared helper: q = LN(slots; ln_slots) @ Wq^T * scale ----------------
__device__ void q_from_slots(const float* s_slot, float* s_tmp,
                             const float* __restrict__ g, const float* __restrict__ bb,
                             const float* __restrict__ Wq, float* __restrict__ qout,
                             int lane, int w)
{
  for (int ss = 0; ss < 2; ++ss) {
    int srow = ss * 4 + w;
    if (srow < 7) {
      float xv = s_slot[srow * 64 + lane];
      float s1 = xv, s2 = xv * xv;
#pragma unroll
      for (int mm = 1; mm < 64; mm <<= 1) {
        s1 += __shfl_xor(s1, mm);
        s2 += __shfl_xor(s2, mm);
      }
      float mean = s1 * 0.015625f;
      float var = s2 * 0.015625f - mean * mean;
      float rs = rsqrtf(var + 1e-5f);
      s_tmp[w * 64 + lane] = (xv - mean) * rs * g[lane] + bb[lane];
    }
    __syncthreads();
    if (srow < 7) {
      float acc = 0.f;
      const float4* wr = (const float4*)(Wq + lane * 64);
      const float4* xr = (const float4*)(s_tmp + w * 64);
#pragma unroll
      for (int i = 0; i < 16; ++i) {
        float4 a = wr[i], xx = xr[i];
        acc += a.x * xx.x + a.y * xx.y + a.z * xx.z + a.w * xx.w;
      }
      qout[srow * 64 + lane] = acc * 0.125f;
    }
    __syncthreads();
  }
}

// ---------------- init ----------------
__global__ __launch_bounds__(256) void init_kernel(
    const float* __restrict__ mu, const float* __restrict__ lsig,
    const float* __restrict__ nslots, const float* __restrict__ nh,
    const float* __restrict__ ln_s_g, const float* __restrict__ ln_s_b,
    const float* __restrict__ Wq,
    float* __restrict__ qbuf, float* __restrict__ h0b)
{
  __shared__ float s_slot[448];
  __shared__ float s_tmp[256];
  const int b = blockIdx.x, t = threadIdx.x, lane = t & 63, w = t >> 6;
  for (int o = t; o < 448; o += 256) {
    int d = o & 63;
    s_slot[o] = mu[d] + expf(lsig[d]) * nslots[b * 448 + o];
  }
  if (t < 64) h0b[b * 64 + t] = mu[t] + expf(lsig[t]) * nh[b * 64 + t];
  __syncthreads();
  q_from_slots(s_slot, s_tmp, ln_s_g, ln_s_b, Wq, qbuf + b * 448, lane, w);
}

// ---------------- attention pass (MFMA both phases, no atomics) ----------------
// grid (32,32): block = 512 n of one b; 8 waves x 64 n each.
// phase 1: logits[n][s] = mfma(k_frag_global, q_frag); no-max softmax across s
//          (logits are O(1): k,q both come from LN'd inputs, |logit| < ~10 << 88).
// phase 2: upd[s][d]   = mfma(attn_bf16_frag, vT_frag_global); block partial -> Wp/Cp.
__global__ __launch_bounds__(512, 4) void attn_kernel(
    const unsigned short* __restrict__ kb, const unsigned short* __restrict__ vt,
    const float* __restrict__ qbuf,
    float* __restrict__ Wp, float* __restrict__ Cp)
{
  __shared__ __align__(16) unsigned short s_qb[16 * 64];       // q bf16 [s][d], rows 7..15 = 0
  __shared__ __align__(16) unsigned short s_at[8][16 * 72];    // per-wave attn bf16 [s][n]
  __shared__ __align__(16) float s_red[8][448];
  __shared__ float s_cred[8][8];

  const int b = blockIdx.y;
  const int t = threadIdx.x, lane = t & 63, w = t >> 6;
  const int m16 = lane & 15, quad = lane >> 4;

  // stage q as bf16 B-frag source (rows >= 7 zero)
  if (t < 256) {
    int i0 = t * 4;
    int s = i0 >> 6, d0 = i0 & 63;
    float f0 = 0.f, f1 = 0.f, f2 = 0.f, f3 = 0.f;
    if (s < 7) {
      const float* qp = qbuf + b * 448 + s * 64 + d0;
      f0 = qp[0]; f1 = qp[1]; f2 = qp[2]; f3 = qp[3];
    }
    uint2 p;
    p.x = pack2bf(f0, f1);
    p.y = pack2bf(f2, f3);
    *(uint2*)&s_qb[i0] = p;
  }
  __syncthreads();

  bf16x8 bq0 = *(const bf16x8*)&s_qb[m16 * 64 + quad * 8];
  bf16x8 bq1 = *(const bf16x8*)&s_qb[m16 * 64 + 32 + quad * 8];

  const int n0w = blockIdx.x * 512 + w * 64;
  const unsigned short* kbA = kb + ((size_t)b * N_ + n0w) * 64;

  // ---- phase 1: hoist all k loads + MFMAs, then 4 independent softmax chains ----
  bf16x8 ak[4][2];
#pragma unroll
  for (int nt = 0; nt < 4; ++nt) {
    ak[nt][0] = *(const bf16x8*)&kbA[(size_t)(nt * 16 + m16) * 64 + quad * 8];
    ak[nt][1] = *(const bf16x8*)&kbA[(size_t)(nt * 16 + m16) * 64 + 32 + quad * 8];
  }
  floatx4 cc[4];
#pragma unroll
  for (int nt = 0; nt < 4; ++nt) {
    floatx4 c = (floatx4){0.f, 0.f, 0.f, 0.f};
    c = __builtin_amdgcn_mfma_f32_16x16x32_bf16(ak[nt][0], bq0, c, 0, 0, 0);
    c = __builtin_amdgcn_mfma_f32_16x16x32_bf16(ak[nt][1], bq1, c, 0, 0, 0);
    cc[nt] = c;
  }
  // lane holds logits[n = nt*16 + quad*4 + rg][s = m16]; softmax over s (octet shuffles)
  float cl = 0.f;
#pragma unroll
  for (int nt = 0; nt < 4; ++nt) {
    float atv[4];
#pragma unroll
    for (int rg = 0; rg < 4; ++rg) {
      float e = (m16 < 7) ? __expf(cc[nt][rg]) : 0.f;
      float sm = e;
      sm += __shfl_xor(sm, 1);
      sm += __shfl_xor(sm, 2);
      sm += __shfl_xor(sm, 4);
      float a = e * __builtin_amdgcn_rcpf(sm) + 1e-8f;
      atv[rg] = a;
      cl += a;
    }
    if (m16 < 7) {
      uint2 p;
      p.x = pack2bf(atv[0], atv[1]);
      p.y = pack2bf(atv[2], atv[3]);
      *(uint2*)&s_at[w][m16 * 72 + nt * 16 + quad * 4] = p;
    }
  }

  // ---- phase 2: issue vt loads before draining LDS (independent) ----
  bf16x8 bv[2][4];
  const unsigned short* vtB = vt + (size_t)b * 64 * N_ + n0w;
#pragma unroll
  for (int ch = 0; ch < 2; ++ch)
#pragma unroll
    for (int dt = 0; dt < 4; ++dt)
      bv[ch][dt] = *(const bf16x8*)&vtB[(size_t)(dt * 16 + m16) * N_ + ch * 32 + quad * 8];
  // wave-private LDS: ensure attn writes visible before frag reads
  asm volatile("s_waitcnt lgkmcnt(0)" ::: "memory");
  bf16x8 af0 = *(const bf16x8*)&s_at[w][m16 * 72 + quad * 8];
  bf16x8 af1 = *(const bf16x8*)&s_at[w][m16 * 72 + 32 + quad * 8];

  floatx4 acc[4];
#pragma unroll
  for (int dt = 0; dt < 4; ++dt) acc[dt] = (floatx4){0.f, 0.f, 0.f, 0.f};
#pragma unroll
  for (int dt = 0; dt < 4; ++dt)
    acc[dt] = __builtin_amdgcn_mfma_f32_16x16x32_bf16(af0, bv[0][dt], acc[dt], 0, 0, 0);
#pragma unroll
  for (int dt = 0; dt < 4; ++dt)
    acc[dt] = __builtin_amdgcn_mfma_f32_16x16x32_bf16(af1, bv[1][dt], acc[dt], 0, 0, 0);

  // D: lane holds upd[s = quad*4+rg][d = dt*16+m16]; valid s<7 (quad<2)
  if (quad < 2) {
#pragma unroll
    for (int dt = 0; dt < 4; ++dt)
#pragma unroll
      for (int rg = 0; rg < 4; ++rg) {
        int s = quad * 4 + rg;
        if (s < 7) s_red[w][s * 64 + dt * 16 + m16] = acc[dt][rg];
      }
  }
  // cloc: lane's partial for s=m16; combine quads
  cl += __shfl_xor(cl, 16);
  cl += __shfl_xor(cl, 32);
  if (m16 < 7 && quad == 0) s_cred[w][m16] = cl;
  __syncthreads();

  // block partial outputs (plain coalesced stores; summed in slot_update)
  if (t < 448) {
    float v = 0.f;
#pragma unroll
    for (int wv = 0; wv < 8; ++wv) v += s_red[wv][t];
    Wp[((size_t)b * 32 + blockIdx.x) * 448 + t] = v;
  } else if (t < 455) {
    int s = t - 448;
    float c = 0.f;
#pragma unroll
    for (int wv = 0; wv < 8; ++wv) c += s_cred[wv][s];
    Cp[((size_t)b * 32 + blockIdx.x) * 8 + s] = c;
  }
}

// ---------------- slot update ----------------
__global__ __launch_bounds__(256) void slot_update_kernel(
    const float* __restrict__ Wp, const float* __restrict__ Cp,
    const float* __restrict__ h0b,
    const float* __restrict__ w_ih, const float* __restrict__ w_hh,
    const float* __restrict__ b_ih, const float* __restrict__ b_hh,
    const float* __restrict__ ln_m_g, const float* __restrict__ ln_m_b,
    const float* __restrict__ w1, const float* __restrict__ b1,
    const float* __restrict__ w2, const float* __restrict__ b2,
    const float* __restrict__ ln_s_g, const float* __restrict__ ln_s_b,
    const float* __restrict__ Wq,
    float* __restrict__ qbuf, float* __restrict__ out)
{
  const int b = blockIdx.x, t = threadIdx.x, lane = t & 63, w = t >> 6;
  __shared__ float s_whhT[64 * 201];   // w_hh transposed [d][j], pad 201 (conflict-free)
  __shared__ float s_upd[448];
  __shared__ float s_gi[1344];
  __shared__ float s_h[64];
  __shared__ float s_gh[192];
  __shared__ float s_slot[448];
  __shared__ float s_tmp[256];
  __shared__ float s_cs[8];

  // stage w_hhT (coalesced global reads)
  for (int i = t; i < 12288; i += 256) {
    int j = i >> 6, d = i & 63;
    s_whhT[d * 201 + j] = w_hh[i];
  }
  if (t < 7) {
    float cs = 0.f;
#pragma unroll
    for (int p = 0; p < 32; ++p) cs += Cp[((size_t)b * 32 + p) * 8 + t];
    s_cs[t] = cs;
  }
  if (t < 64) s_h[t] = h0b[b * 64 + t];
  __syncthreads();
  // updates = sum of 32 block partials / attn-column-sum
  for (int o = t; o < 448; o += 256) {
    int s = o >> 6;
    float acc = 0.f;
#pragma unroll
    for (int p = 0; p < 32; ++p) acc += Wp[((size_t)b * 32 + p) * 448 + o];
    s_upd[o] = acc / s_cs[s];
  }
  __syncthreads();
  // gi = updates @ w_ih^T + b_ih (float4)
  for (int o = t; o < 1344; o += 256) {
    int s = o / 192, j = o - s * 192;
    float acc = b_ih[j];
    const float4* wr = (const float4*)(w_ih + j * 64);
    const float4* ur = (const float4*)(s_upd + s * 64);
#pragma unroll
    for (int i = 0; i < 16; ++i) {
      float4 a = wr[i], u = ur[i];
      acc += a.x * u.x + a.y * u.y + a.z * u.z + a.w * u.w;
    }
    s_gi[o] = acc;
  }
  __syncthreads();
  // GRU over slots (gate order r,z,n)
  for (int s = 0; s < 7; ++s) {
    if (t < 192) {
      float acc = b_hh[t];
#pragma unroll 16
      for (int d = 0; d < 64; ++d) acc += s_h[d] * s_whhT[d * 201 + t];
      s_gh[t] = acc;
    }
    __syncthreads();
    if (t < 64) {
      float ir = s_gi[s * 192 + t], iz = s_gi[s * 192 + 64 + t], inn = s_gi[s * 192 + 128 + t];
      float hr = s_gh[t], hz = s_gh[64 + t], hn = s_gh[128 + t];
      float r = 1.f / (1.f + expf(-(ir + hr)));
      float z = 1.f / (1.f + expf(-(iz + hz)));
      float n = tanhf(inn + r * hn);
      float hnew = (1.f - z) * n + z * s_h[t];
      s_slot[s * 64 + t] = hnew;
      s_h[t] = hnew;
    }
    __syncthreads();
  }
  // MLP with residual
  float* s_sn = s_gi;
  float* s_hid = s_gi + 448;
  for (int ss = 0; ss < 2; ++ss) {
    int srow = ss * 4 + w;
    if (srow < 7) {
      float xv = s_slot[srow * 64 + lane];
      float s1 = xv, s2 = xv * xv;
#pragma unroll
      for (int mm = 1; mm < 64; mm <<= 1) {
        s1 += __shfl_xor(s1, mm);
        s2 += __shfl_xor(s2, mm);
      }
      float mean = s1 * 0.015625f;
      float var = s2 * 0.015625f - mean * mean;
      float rs = rsqrtf(var + 1e-5f);
      s_sn[srow * 64 + lane] = (xv - mean) * rs * ln_m_g[lane] + ln_m_b[lane];
    }
  }
  __syncthreads();
  for (int o = t; o < 896; o += 256) {
    int s = o >> 7, hh = o & 127;
    float acc = b1[hh];
    const float4* wr = (const float4*)(w1 + hh * 64);
    const float4* xr = (const float4*)(s_sn + s * 64);
#pragma unroll
    for (int i = 0; i < 16; ++i) {
      float4 a = wr[i], xx = xr[i];
      acc += a.x * xx.x + a.y * xx.y + a.z * xx.z + a.w * xx.w;
    }
    s_hid[o] = fmaxf(acc, 0.f);
  }
  __syncthreads();
  for (int o = t; o < 448; o += 256) {
    int s = o >> 6, d = o & 63;
    float acc = b2[d];
    const float4* wr = (const float4*)(w2 + d * 128);
    const float4* hr = (const float4*)(s_hid + s * 128);
#pragma unroll
    for (int i = 0; i < 32; ++i) {
      float4 a = wr[i], hv = hr[i];
      acc += a.x * hv.x + a.y * hv.y + a.z * hv.z + a.w * hv.w;
    }
    float val = s_slot[o] + acc;
    s_slot[o] = val;
    out[b * 448 + o] = val;
  }
  __syncthreads();
  q_from_slots(s_slot, s_tmp, ln_s_g, ln_s_b, Wq, qbuf + b * 448, lane, w);
}

extern "C" void kernel_launch(void* const* d_in, const int* in_sizes, int n_in,
                              void* d_out, int out_size, void* d_ws, size_t ws_size,
                              hipStream_t stream)
{
  (void)in_sizes; (void)n_in; (void)out_size; (void)ws_size;
  const float* x      = (const float*)d_in[0];
  const float* ln_in_g = (const float*)d_in[1];
  const float* ln_in_b = (const float*)d_in[2];
  const float* ln_s_g  = (const float*)d_in[3];
  const float* ln_s_b  = (const float*)d_in[4];
  const float* ln_m_g  = (const float*)d_in[5];
  const float* ln_m_b  = (const float*)d_in[6];
  const float* Wq = (const float*)d_in[7];
  const float* Wk = (const float*)d_in[8];
  const float* Wv = (const float*)d_in[9];
  const float* mu = (const float*)d_in[10];
  const float* lsig = (const float*)d_in[11];
  const float* w_ih = (const float*)d_in[12];
  const float* w_hh = (const float*)d_in[13];
  const float* b_ih = (const float*)d_in[14];
  const float* b_hh = (const float*)d_in[15];
  const float* w1 = (const float*)d_in[16];
  const float* b1 = (const float*)d_in[17];
  const float* w2 = (const float*)d_in[18];
  const float* b2 = (const float*)d_in[19];
  const float* nslots = (const float*)d_in[20];
  const float* nh = (const float*)d_in[21];

  unsigned short* kb = (unsigned short*)d_ws;                 // k[b][n][d] bf16
  unsigned short* vt = kb + (size_t)B_ * N_ * D_;             // vT[b][d][n] bf16
  float* fb = (float*)(vt + (size_t)B_ * N_ * D_);
  float* qbuf = fb;              // 32*448
  float* h0b  = fb + 14336;      // 32*64
  float* Wp   = fb + 16384;      // 32*32*448 block partials
  float* Cp   = Wp + 458752;     // 32*32*8 block partials
  float* out = (float*)d_out;

  proj_kernel<<<4096, 256, 0, stream>>>(x, ln_in_g, ln_in_b, Wk, Wv, kb, vt);
  init_kernel<<<32, 256, 0, stream>>>(mu, lsig, nslots, nh, ln_s_g, ln_s_b, Wq,
                                      qbuf, h0b);
  for (int it = 0; it < 3; ++it) {
    attn_kernel<<<dim3(32, 32), 512, 0, stream>>>(kb, vt, qbuf, Wp, Cp);
    slot_update_kernel<<<32, 256, 0, stream>>>(Wp, Cp, h0b, w_ih, w_hh, b_ih, b_hh,
                                               ln_m_g, ln_m_b, w1, b1, w2, b2,
                                               ln_s_g, ln_s_b, Wq, qbuf, out);
  }
}